// Round 5
// baseline (24.793 us; speedup 1.0000x reference)
//
#include <hip/hip_runtime.h>

// diff_round(x) = x - sin(2*pi*x)/(2*pi).
// v_sin_f32 input is in REVOLUTIONS: __builtin_amdgcn_sinf(x) == sin(2*pi*x).
#define INV_TWO_PI_F 0.15915494309189533577f

__device__ __forceinline__ float dround(float x) {
    return __builtin_fmaf(__builtin_amdgcn_sinf(x), -INV_TWO_PI_F, x);
}

// One 64-lane wave per area. Fully-coalesced mapping: lane t owns pixels
// q = t + 64k (k=0..3)  ->  row r = (t>>4) + 4k, col c = t & 15.
// Every load/store instruction covers a CONTIGUOUS address range
// (mask: 4 x 1KB dwordx4; img/edge/out: 4 x 256B dword).
// mid is exactly {0,1} (jnp.round of uniform); hdround fixes {0,1}, and
// dround(1-x) == 1-dround(x), so differentiable_eq(m, mid) reduces to
// select(mid, d5(m), 1-d5(m)) at the point feeding differentiable_and.
__global__ void __launch_bounds__(256, 8)
deconv_area_kernel(const float* __restrict__ img,
                   const float* __restrict__ mask,
                   const float* __restrict__ mid,
                   const float* __restrict__ edge,
                   float* __restrict__ out_edges,
                   float* __restrict__ out_scalar)
{
    const int wid = blockIdx.x * 4 + (threadIdx.x >> 6);  // area index
    const int t   = threadIdx.x & 63;
    const size_t p = (size_t)wid;

    // ---- issue all loads up front (all fully coalesced) ----
    const float4* maskv = reinterpret_cast<const float4*>(mask) + p * 256;
    const float4 mm0 = maskv[t];
    const float4 mm1 = maskv[t + 64];
    const float4 mm2 = maskv[t + 128];
    const float4 mm3 = maskv[t + 192];
    const float* imgp  = img  + p * 256;
    const float* edgep = edge + p * 256;
    float imv[4], edv[4];
    #pragma unroll
    for (int k = 0; k < 4; ++k) {
        imv[k] = imgp [t + 64 * k];
        edv[k] = edgep[t + 64 * k];
    }
    const float4 md = reinterpret_cast<const float4*>(mid)[p];   // broadcast

    const bool h0 = md.x > 0.5f;
    const bool h1 = md.y > 0.5f;
    const bool h2 = md.z > 0.5f;
    const bool h3 = md.w > 0.5f;

    const float4 mm[4] = {mm0, mm1, mm2, mm3};

    // ---- filter_mask_of_intrest per pixel ----
    float mc[4], mi[4];
    #pragma unroll
    for (int k = 0; k < 4; ++k) {
        float w0 = mm[k].x, w1 = mm[k].y, w2 = mm[k].z, w3 = mm[k].w;
        #pragma unroll
        for (int r = 0; r < 5; ++r) {
            w0 = dround(w0); w1 = dround(w1); w2 = dround(w2); w3 = dround(w3);
        }
        const float da0 = h0 ? w0 : 1.0f - w0;
        const float da1 = h1 ? w1 : 1.0f - w1;
        const float da2 = h2 ? w2 : 1.0f - w2;
        const float da3 = h3 ? w3 : 1.0f - w3;
        mc[k] = dround(da0 * da1) * dround(da2 * da3);
        mi[k] = mc[k] * imv[k];
    }

    // ---- reduction 1 (butterfly -> all lanes): sum(mc), sum(mc*img) ----
    float s1 = mc[0] + mc[1] + mc[2] + mc[3];
    float s2 = mi[0] + mi[1] + mi[2] + mi[3];
    #pragma unroll
    for (int m = 1; m < 64; m <<= 1) {
        s1 += __shfl_xor(s1, m);
        s2 += __shfl_xor(s2, m);
    }
    const float inv_d = __builtin_amdgcn_rcpf(s1 + 1e-8f);
    const float meann = s2 * inv_d;

    // ---- neighbors (zero-padded shifts) ----
    // row r-1 = pixel q-16: lane t-16 (same k)  or lane t+48 (k-1) when t<16
    // row r+1 = pixel q+16: lane t+16 (same k)  or lane t-48 (k+1) when t>=48
    // col c-1 / c+1 = lane t-1 / t+1 (same k), masked at c==0 / c==15
    float pr[4], nr[4], lf[4], rt[4];
    #pragma unroll
    for (int k = 0; k < 4; ++k) {
        const float up16 = __shfl_up(mc[k], 16);
        const float dn16 = __shfl_down(mc[k], 16);
        const float prWrap = (k > 0) ? __shfl_down(mc[k - 1], 48) : 0.0f;
        const float nrWrap = (k < 3) ? __shfl_up(mc[k + 1], 48) : 0.0f;
        pr[k] = (t >= 16) ? up16 : prWrap;
        nr[k] = (t <  48) ? dn16 : nrWrap;
        const float l1 = __shfl_up(mc[k], 1);
        const float r1_ = __shfl_down(mc[k], 1);
        lf[k] = ((t & 15) > 0)  ? l1  : 0.0f;
        rt[k] = ((t & 15) < 15) ? r1_ : 0.0f;
    }

    // ---- erosion + masked edges + reduction-2 partials ----
    float me[4];
    float r1 = 0.0f, r2 = 0.0f;
    #pragma unroll
    for (int k = 0; k < 4; ++k) {
        const float ed_fb = 1.0f - (nr[k] * pr[k] + (1.0f - nr[k]) * (1.0f - pr[k]));
        const float ed_ud = 1.0f - (rt[k] * lf[k] + (1.0f - rt[k]) * (1.0f - lf[k]));
        const float s0a = ed_fb * mc[k];
        const float s0b = ed_ud * mc[k];
        const float sb0 = s0a * s0b + (1.0f - s0a) * s0a + (1.0f - s0b) * s0a;
        me[k] = (1.0f - sb0) * mc[k] * edv[k];
        const float vv = (mi[k] - meann) * mc[k];
        r1 += vv * vv;
        r2 += me[k];
    }

    // coalesced stores (4 x 256B contiguous)
    float* outp = out_edges + p * 256;
    #pragma unroll
    for (int k = 0; k < 4; ++k) outp[t + 64 * k] = me[k];

    // ---- reduction 2 (butterfly): sum(var-terms), sum(masked_edges) ----
    #pragma unroll
    for (int m = 1; m < 64; m <<= 1) {
        r1 += __shfl_xor(r1, m);
        r2 += __shfl_xor(r2, m);
    }
    if (t == 0) {
        const float varr = r1 * inv_d;
        const float loss = r2 * (1.0f / 256.0f);
        out_scalar[p] = varr * loss * 1000.0f;
    }
}

extern "C" void kernel_launch(void* const* d_in, const int* in_sizes, int n_in,
                              void* d_out, int out_size, void* d_ws, size_t ws_size,
                              hipStream_t stream)
{
    const float* img  = (const float*)d_in[0];  // [B,A,16,16,1]
    const float* mask = (const float*)d_in[1];  // [B,A,16,16,4]
    const float* mid  = (const float*)d_in[2];  // [B,A,4]
    const float* edge = (const float*)d_in[3];  // [B,A,16,16]

    const int n_areas = in_sizes[3] / 256;      // B*A (16384)

    float* out0 = (float*)d_out;                         // [B,A,16,16,1]
    float* out1 = (float*)d_out + (size_t)n_areas * 256; // [B,A]

    deconv_area_kernel<<<dim3(n_areas / 4), dim3(256), 0, stream>>>(
        img, mask, mid, edge, out0, out1);
}